// Round 1
// baseline (128.387 us; speedup 1.0000x reference)
//
#include <hip/hip_runtime.h>
#include <math.h>

// fab_penalty_ls_curve — R5: kill the issue-rate bottleneck.
// R4 counters: VALUBusy 53%, HBM 10.5%, 0 bank conflicts => issue/latency bound.
// Back-computed ~125 lane-inst/point vs ~40 of real math: the 13 scalar loads
// per point + their 64-bit address arithmetic dominate. R5 restructures to
// 4 cols/thread (float4 + 2x float2 halo loads per ROW of 4 points) with a
// 5-row rolling register ring (fully unrolled => static indices => VGPRs, no
// scratch). Loads: 13/point -> ~1.1 inst/point. Mirror seam & column clamps
// become register substitutions (left halo = {v.x,v.x}, right halo = {v.w,v.z}).
// Y-boundary strips (2 of 512) run the same ring with clamped row pointers.
// Reduction plumbing unchanged from R4 (plain per-block partial stores ->
// tiny finish kernel; device-atomic finish was R2/R3's 3x regression).
// Assumes Wn % (BLOCK_X*COLS) == 0 and Hn % ROWS_PER == 0 (4096x4096 input).

#define BLOCK_X 256
#define COLS 4
#define ROWS_PER 8

// atan(v / c) with v > 0, given rv ~= 1/v (reused from k = num*rv^3).
// Max abs error ~1e-5 rad; error budget is ~1e3x larger (2% on the sum).
__device__ __forceinline__ float fast_atan_ratio(float v, float c, float rv)
{
    const float rc = __builtin_amdgcn_rcpf(c);
    const float q  = v * rc;        // v/c (sign = sign(c))
    const float iq = c * rv;        // c/v = 1/q, no extra rcp
    const bool  big = fabsf(q) > 1.0f;
    const float t  = big ? iq : q;
    const float s  = t * t;
    float p = fmaf(s, -0.01172120f, 0.05265332f);
    p = fmaf(s, p, -0.11643287f);
    p = fmaf(s, p,  0.19354346f);
    p = fmaf(s, p, -0.33262347f);
    p = fmaf(s, p,  0.99997726f);
    const float at = p * t;
    const float hp = copysignf(1.57079632679f, q);
    return big ? (hp - at) : at;    // atan(q) = sign(q)*pi/2 - atan(1/q), |q|>1
}

// Load cols [c-2 .. c+5] of one row into h8[0..7].
// left  (c==0):    cols -2,-1 clamp to col 0  -> {v.x, v.x}, no load.
// right (c+4==Wn): cols Wn,Wn+1 mirror to Wn-1,Wn-2 -> {v.w, v.z}, no load.
__device__ __forceinline__ void load_row8(float h8[8], const float* __restrict__ rowp,
                                          bool left, bool right)
{
    const float4 v = *reinterpret_cast<const float4*>(rowp);
    float2 lo, hi;
    if (left)  { lo.x = v.x; lo.y = v.x; }
    else         lo = *reinterpret_cast<const float2*>(rowp - 2);
    if (right) { hi.x = v.w; hi.y = v.z; }
    else         hi = *reinterpret_cast<const float2*>(rowp + 4);
    h8[0]=lo.x; h8[1]=lo.y; h8[2]=v.x; h8[3]=v.y; h8[4]=v.z; h8[5]=v.w; h8[6]=hi.x; h8[7]=hi.y;
}

// One output point. A,B,C,D,E = rows i-2,i-1,i,i+1,i+2 (8-wide, cols c-2..c+5),
// m = in-register column index of this point (2..5). Math identical to R4.
__device__ __forceinline__ float point_cc(
    const float* A, const float* B, const float* C, const float* D, const float* E,
    int m, float sxi, float sxm, float sxp, float syj, float sym, float syp,
    bool jz, bool itop, bool ibot)
{
    const float SC     = 1e-12f;
    const float FLOORV = (float)(1e-32 / 6.0);
    const float pi_d   = 3.14159265358979323846f / 1.1f;

    const float ex = fmaf(D[m] - B[m], sxi, SC);
    const float ey = fmaf(C[m+1] - C[m-1], syj, SC);
    float exn = fmaf(C[m] - A[m], sxm, SC);
    float exs = fmaf(E[m] - C[m], sxp, SC);
    if (itop) exn = ex;              // im == i at top boundary
    if (ibot) exs = ex;              // ip == i at bottom boundary
    const float exx = (exs - exn) * sxi;
    float eyw = fmaf(C[m] - C[m-2], sym, SC);
    const float eye = fmaf(C[m+2] - C[m], syp, SC);
    if (jz) eyw = ey;                // jm == j at left boundary
    const float eyy = (eye - eyw) * syj;
    const float exy = ((D[m+1] - B[m+1]) - (D[m-1] - B[m-1])) * (sxi * syj);

    const float t1 = ex * ex, t2 = ey * ey;
    float num = t1 * eyy;
    num = fmaf(t2, exx, num);
    num = fmaf(-2.0f * (ex * ey), exy, num);
    float ev = __builtin_amdgcn_sqrtf(t1 + t2);
    ev = fmaxf(ev, FLOORV);
    const float rv = __builtin_amdgcn_rcpf(ev);
    const float k  = num * (rv * rv) * rv;
    const float at = fast_atan_ratio(ev, C[m], rv);
    const float cc = fabsf(k * at) - pi_d;
    return fmaxf(cc, 0.0f);          // fmax(NaN,0)=0 -> nansum semantics
}

// One ROWS_PER strip for 4 columns. YB=false: pure-interior rows, single
// incrementing row pointer. YB=true: clamped row indices + one-sided scales
// (only first/last gy blocks). Fully unrolled so the (r+k)%5 ring indices are
// compile-time => h stays in VGPRs (rule: no runtime-indexed register arrays).
template<bool YB>
__device__ __forceinline__ float strip_compute(
    const float* __restrict__ eps, int Hn, int Wn, int i0, int c,
    bool left, bool right, float rd, float rd2)
{
    const float syj0 = left ? rd : rd2;   // j==0: forward diff scale
    const float sym1 = left ? rd : rd2;   // j==1: jm==0 -> forward-diff eps_y[0]

    float h[5][8];
    const float* base = eps + c;
    const float* pr = YB ? base : (base + (ptrdiff_t)(i0 - 2) * Wn);

    #pragma unroll
    for (int q = 0; q < 4; ++q) {         // preload rows i0-2 .. i0+1
        const float* p;
        if (YB) {
            int t = i0 - 2 + q;
            t = t < 0 ? 0 : t;
            t = t > Hn - 1 ? Hn - 1 : t;
            p = base + (size_t)t * (size_t)Wn;
        } else {
            p = pr;
        }
        load_row8(h[q], p, left, right);
        if (!YB) pr += Wn;
    }
    // !YB: pr now points at row i0+2 (first incoming row)

    float acc = 0.0f;
    #pragma unroll
    for (int r = 0; r < ROWS_PER; ++r) {
        const float* p;
        if (YB) {
            int t = i0 + r + 2;
            t = t > Hn - 1 ? Hn - 1 : t;
            p = base + (size_t)t * (size_t)Wn;
        } else {
            p = pr;
        }
        load_row8(h[(r + 4) % 5], p, left, right);
        if (!YB) pr += Wn;

        float sxi = rd2, sxm = rd2, sxp = rd2;
        bool itop = false, ibot = false;
        if (YB) {
            const int i = i0 + r;
            itop = (i == 0); ibot = (i == Hn - 1);
            sxi = (itop || ibot) ? rd : rd2;
            sxm = (i == 1) ? rd : rd2;        // im == 0
            sxp = (i == Hn - 2) ? rd : rd2;   // ip == Hn-1
        }
        const float* A = h[(r + 0) % 5];  // i-2
        const float* B = h[(r + 1) % 5];  // i-1
        const float* C = h[(r + 2) % 5];  // i
        const float* D = h[(r + 3) % 5];  // i+1
        const float* E = h[(r + 4) % 5];  // i+2
        acc += point_cc(A, B, C, D, E, 2, sxi, sxm, sxp, syj0, rd2,  rd2, left,  itop, ibot);
        acc += point_cc(A, B, C, D, E, 3, sxi, sxm, sxp, rd2,  sym1, rd2, false, itop, ibot);
        acc += point_cc(A, B, C, D, E, 4, sxi, sxm, sxp, rd2,  rd2,  rd2, false, itop, ibot);
        acc += point_cc(A, B, C, D, E, 5, sxi, sxm, sxp, rd2,  rd2,  rd2, false, itop, ibot);
    }
    return acc;
}

__global__ __launch_bounds__(BLOCK_X) void curve_partial_kernel(
    const float* __restrict__ eps, const float* __restrict__ gs,
    double* __restrict__ partial, int Hn, int Wn)
{
    const int tx = threadIdx.x;
    const int c  = (blockIdx.x * BLOCK_X + tx) * COLS;
    const int i0 = blockIdx.y * ROWS_PER;
    const float d   = gs[0];
    const float rd  = 1.0f / d;
    const float rd2 = 0.5f * rd;
    const bool left  = (c == 0);
    const bool right = (c + COLS == Wn);

    // rows touched: i0-2 .. i0+ROWS_PER+1
    const bool yint = (i0 >= 2) && (i0 + ROWS_PER + 1 < Hn);
    const float accf = yint
        ? strip_compute<false>(eps, Hn, Wn, i0, c, left, right, rd, rd2)
        : strip_compute<true >(eps, Hn, Wn, i0, c, left, right, rd, rd2);

    double acc = (double)accf;
    #pragma unroll
    for (int off = 32; off > 0; off >>= 1)
        acc += __shfl_down(acc, off, 64);
    __shared__ double lds[BLOCK_X / 64];
    const int lane = tx & 63, wv = tx >> 6;
    if (lane == 0) lds[wv] = acc;
    __syncthreads();
    if (tx == 0) {
        // plain store — NO device-scope atomics (R2/R3's 3x regression)
        partial[blockIdx.y * gridDim.x + blockIdx.x] =
            lds[0] + lds[1] + lds[2] + lds[3];
    }
}

__global__ __launch_bounds__(256) void curve_finish_kernel(
    const double* __restrict__ partial, int n,
    const float* __restrict__ gs, float* __restrict__ out)
{
    const int tx = threadIdx.x;
    double acc = 0.0;
    for (int idx = tx; idx < n; idx += 256) acc += partial[idx];
    #pragma unroll
    for (int off = 32; off > 0; off >>= 1)
        acc += __shfl_down(acc, off, 64);
    __shared__ double lds[4];
    const int lane = tx & 63, wv = tx >> 6;
    if (lane == 0) lds[wv] = acc;
    __syncthreads();
    if (tx == 0) {
        const double dd = (double)gs[0];
        // x2 for the mirrored half; x d^2 for grid_size^2 (ALPHA=1)
        out[0] = (float)((lds[0] + lds[1] + lds[2] + lds[3]) * 2.0 * dd * dd);
    }
}

extern "C" void kernel_launch(void* const* d_in, const int* in_sizes, int n_in,
                              void* d_out, int out_size, void* d_ws, size_t ws_size,
                              hipStream_t stream) {
    const float* eps = (const float*)d_in[0];
    const float* gs  = (const float*)d_in[1];
    float* out = (float*)d_out;

    const int n = in_sizes[0];
    int Wn = (int)(sqrt((double)n) + 0.5);   // 4096 for 4096x4096
    int Hn = n / Wn;

    const int gx = Wn / (BLOCK_X * COLS);            // 4
    const int gy = (Hn + ROWS_PER - 1) / ROWS_PER;   // 512
    double* partial = (double*)d_ws;   // gx*gy slots, ALL written every launch

    curve_partial_kernel<<<dim3(gx, gy), BLOCK_X, 0, stream>>>(eps, gs, partial, Hn, Wn);
    curve_finish_kernel<<<1, 256, 0, stream>>>(partial, gx * gy, gs, out);
}